// Round 2
// baseline (1006.829 us; speedup 1.0000x reference)
//
#include <hip/hip_runtime.h>

// GraphPooling: voxel-grid pooling.
//  inputs: x[N,64] f32, pos[N,3] f32, edge_index[E,2] i32, batch[N] i32
//  outputs (concat, all read back as f32): pooled_x[M,64], pos_mean[M,3],
//    ei_out[Ed+M,2], new_batch[M]
// Keyspace: key = ((b*s0+qx)*s1+qy)*s2+qz < 16*32*32*32 = 524288.

#define KSP 524288
#define SCAN_BLOCK 256
#define SCAN_ITEMS 16
#define SCAN_CHUNK 4096            // SCAN_BLOCK * SCAN_ITEMS
#define NCHUNK (KSP / SCAN_CHUNK)  // 128
#define SCAP 4096                  // per-block LDS cap for bucket sort

// ws header slots (u32)
// [0..2] = max qpos per axis, [3] = M, [4] = validE, [5] = Ed

__device__ __forceinline__ unsigned encF(float f) {
  unsigned u = __float_as_uint(f);
  return (u & 0x80000000u) ? ~u : (u | 0x80000000u);
}
__device__ __forceinline__ float decF(unsigned u) {
  return (u & 0x80000000u) ? __uint_as_float(u & 0x7FFFFFFFu)
                           : __uint_as_float(~u);
}

// ---- per-point: max of quantized coords (block-reduced) ----
__global__ void k_qmax(const float* __restrict__ pos, unsigned* hdr, int N) {
  __shared__ unsigned sm[3];
  if (threadIdx.x < 3) sm[threadIdx.x] = 0;
  __syncthreads();
  int i = blockIdx.x * blockDim.x + threadIdx.x;
  if (i < N) {
    int q0 = (int)floorf(pos[3 * i + 0] * 0.25f);
    int q1 = (int)floorf(pos[3 * i + 1] * 0.25f);
    int q2 = (int)floorf(pos[3 * i + 2] * 0.25f);
    atomicMax(&sm[0], (unsigned)q0);
    atomicMax(&sm[1], (unsigned)q1);
    atomicMax(&sm[2], (unsigned)q2);
  }
  __syncthreads();
  if (threadIdx.x < 3) atomicMax(&hdr[threadIdx.x], sm[threadIdx.x]);
}

// ---- per-point: linearized voxel key + histogram ----
__global__ void k_keys(const float* __restrict__ pos, const int* __restrict__ batch,
                       const unsigned* __restrict__ hdr, unsigned* __restrict__ key,
                       unsigned* __restrict__ cnt, int N) {
  int i = blockIdx.x * blockDim.x + threadIdx.x;
  if (i >= N) return;
  unsigned s0 = hdr[0] + 1, s1 = hdr[1] + 1, s2 = hdr[2] + 1;
  unsigned q0 = (unsigned)(int)floorf(pos[3 * i + 0] * 0.25f);
  unsigned q1 = (unsigned)(int)floorf(pos[3 * i + 1] * 0.25f);
  unsigned q2 = (unsigned)(int)floorf(pos[3 * i + 2] * 0.25f);
  unsigned k = (((unsigned)batch[i] * s0 + q0) * s1 + q1) * s2 + q2;
  key[i] = k;
  atomicAdd(&cnt[k], 1u);
}

// ---- generic 3-phase exclusive scan ----
__global__ void scanA(const unsigned* __restrict__ in, unsigned* __restrict__ out,
                      unsigned* __restrict__ chunkSums, int n, int presence) {
  __shared__ unsigned lds[SCAN_BLOCK];
  int base = blockIdx.x * SCAN_CHUNK;
  int tbase = base + threadIdx.x * SCAN_ITEMS;
  unsigned vals[SCAN_ITEMS];
  unsigned sum = 0;
  for (int i = 0; i < SCAN_ITEMS; ++i) {
    unsigned v = 0;
    int idx = tbase + i;
    if (idx < n) { v = in[idx]; if (presence) v = v ? 1u : 0u; }
    vals[i] = sum;
    sum += v;
  }
  lds[threadIdx.x] = sum;
  __syncthreads();
  for (int off = 1; off < SCAN_BLOCK; off <<= 1) {
    unsigned t = (threadIdx.x >= (unsigned)off) ? lds[threadIdx.x - off] : 0u;
    __syncthreads();
    lds[threadIdx.x] += t;
    __syncthreads();
  }
  unsigned threadExcl = lds[threadIdx.x] - sum;
  for (int i = 0; i < SCAN_ITEMS; ++i) {
    int idx = tbase + i;
    if (idx < n) out[idx] = threadExcl + vals[i];
  }
  if (threadIdx.x == SCAN_BLOCK - 1) chunkSums[blockIdx.x] = lds[SCAN_BLOCK - 1];
}

// scanA variant for edge dedup: keep(e) = first entry or (src,dst) differs from e-1
__global__ void scanAE(const unsigned* __restrict__ src, const unsigned* __restrict__ dst,
                       unsigned* __restrict__ out, unsigned* __restrict__ chunkSums,
                       const unsigned* __restrict__ hdr) {
  __shared__ unsigned lds[SCAN_BLOCK];
  int n = (int)hdr[4];
  int base = blockIdx.x * SCAN_CHUNK;
  int tbase = base + threadIdx.x * SCAN_ITEMS;
  unsigned vals[SCAN_ITEMS];
  unsigned sum = 0;
  for (int i = 0; i < SCAN_ITEMS; ++i) {
    unsigned v = 0;
    int idx = tbase + i;
    if (idx < n) {
      if (idx == 0) v = 1u;
      else v = (src[idx] != src[idx - 1] || dst[idx] != dst[idx - 1]) ? 1u : 0u;
    }
    vals[i] = sum;
    sum += v;
  }
  lds[threadIdx.x] = sum;
  __syncthreads();
  for (int off = 1; off < SCAN_BLOCK; off <<= 1) {
    unsigned t = (threadIdx.x >= (unsigned)off) ? lds[threadIdx.x - off] : 0u;
    __syncthreads();
    lds[threadIdx.x] += t;
    __syncthreads();
  }
  unsigned threadExcl = lds[threadIdx.x] - sum;
  for (int i = 0; i < SCAN_ITEMS; ++i) {
    int idx = tbase + i;
    if (idx < n) out[idx] = threadExcl + vals[i];
  }
  if (threadIdx.x == SCAN_BLOCK - 1) chunkSums[blockIdx.x] = lds[SCAN_BLOCK - 1];
}

__global__ void scanB(unsigned* chunkSums, unsigned* totalDst, int nchunks) {
  __shared__ unsigned lds[1024];
  unsigned v = (threadIdx.x < (unsigned)nchunks) ? chunkSums[threadIdx.x] : 0u;
  lds[threadIdx.x] = v;
  __syncthreads();
  for (int off = 1; off < 1024; off <<= 1) {
    unsigned t = (threadIdx.x >= (unsigned)off) ? lds[threadIdx.x - off] : 0u;
    __syncthreads();
    lds[threadIdx.x] += t;
    __syncthreads();
  }
  if (threadIdx.x < (unsigned)nchunks) chunkSums[threadIdx.x] = lds[threadIdx.x] - v;
  if (threadIdx.x == 0 && totalDst) *totalDst = lds[1023];
}

__global__ void scanC(unsigned* __restrict__ out, unsigned* __restrict__ out2,
                      const unsigned* __restrict__ chunkSums, int n) {
  int idx = blockIdx.x * blockDim.x + threadIdx.x;
  if (idx >= n) return;
  unsigned v = out[idx] + chunkSums[idx / SCAN_CHUNK];
  out[idx] = v;
  if (out2) out2[idx] = v;
}

__global__ void scanCE(unsigned* __restrict__ out, const unsigned* __restrict__ chunkSums,
                       const unsigned* __restrict__ hdr) {
  int idx = blockIdx.x * blockDim.x + threadIdx.x;
  if (idx >= (int)hdr[4]) return;
  out[idx] += chunkSums[idx / SCAN_CHUNK];
}

// ---- build rank -> key map ----
__global__ void k_ukey(const unsigned* __restrict__ cnt, const unsigned* __restrict__ rank,
                       unsigned* __restrict__ ukeyArr) {
  int k = blockIdx.x * blockDim.x + threadIdx.x;
  if (k >= KSP) return;
  if (cnt[k]) ukeyArr[rank[k]] = (unsigned)k;
}

// ---- per-point: inv index + pos accumulation into d_out ----
__global__ void k_inv_pos(const unsigned* __restrict__ key, const unsigned* __restrict__ rank,
                          unsigned* __restrict__ inv, const float* __restrict__ pos,
                          float* __restrict__ out, const unsigned* __restrict__ hdr, int N) {
  int i = blockIdx.x * blockDim.x + threadIdx.x;
  if (i >= N) return;
  unsigned m = rank[key[i]];
  inv[i] = m;
  unsigned M = hdr[3];
  unsigned long long O1 = 64ull * M;
  atomicAdd(&out[O1 + 3ull * m + 0], pos[3 * i + 0]);
  atomicAdd(&out[O1 + 3ull * m + 1], pos[3 * i + 1]);
  atomicAdd(&out[O1 + 3ull * m + 2], pos[3 * i + 2]);
}

// ---- per-(point,feature): encoded atomic max into d_out[0 .. M*64) ----
__global__ void k_xmax(const float* __restrict__ x, const unsigned* __restrict__ inv,
                       float* __restrict__ out, long long total) {
  long long t = (long long)blockIdx.x * blockDim.x + threadIdx.x;
  if (t >= total) return;
  int i = (int)(t >> 6);
  int d = (int)(t & 63);
  unsigned m = inv[i];
  unsigned e = encF(x[t]);
  atomicMax((unsigned*)&out[(unsigned long long)m * 64u + d], e);
}

// ---- decode pooled_x in place ----
__global__ void k_decode(float* __restrict__ out, const unsigned* __restrict__ hdr) {
  long long idx = (long long)blockIdx.x * blockDim.x + threadIdx.x;
  unsigned M = hdr[3];
  if (idx >= (long long)M * 64) return;
  unsigned u = __float_as_uint(out[idx]);
  out[idx] = decF(u);
}

// ---- pos mean: divide by counts ----
__global__ void k_posdiv(float* __restrict__ out, const unsigned* __restrict__ hdr,
                         const unsigned* __restrict__ ukeyArr, const unsigned* __restrict__ cnt) {
  int m = blockIdx.x * blockDim.x + threadIdx.x;
  unsigned M = hdr[3];
  if ((unsigned)m >= M) return;
  float c = (float)cnt[ukeyArr[m]];
  unsigned long long O1 = 64ull * M;
  out[O1 + 3ull * m + 0] /= c;
  out[O1 + 3ull * m + 1] /= c;
  out[O1 + 3ull * m + 2] /= c;
}

// ---- edges: map endpoints to voxel ranks ONCE; cache + histogram ----
__global__ void k_emap(const int* __restrict__ ei, const unsigned* __restrict__ inv,
                       unsigned* __restrict__ edgeSrc, unsigned* __restrict__ eStage,
                       unsigned* __restrict__ bucketCnt, int E) {
  int e = blockIdx.x * blockDim.x + threadIdx.x;
  if (e >= E) return;
  unsigned a = inv[ei[2 * e]];
  unsigned b = inv[ei[2 * e + 1]];
  edgeSrc[e] = a;
  eStage[e] = b;
  if (a != b) atomicAdd(&bucketCnt[a], 1u);
}

// ---- edges: scatter dst into per-src buckets (coalesced re-read of cache) ----
__global__ void k_escatter(const unsigned* __restrict__ edgeSrc, const unsigned* __restrict__ eStage,
                           unsigned* __restrict__ cursor, unsigned* __restrict__ edgeVal, int E) {
  int e = blockIdx.x * blockDim.x + threadIdx.x;
  if (e >= E) return;
  unsigned a = edgeSrc[e];
  unsigned b = eStage[e];
  if (a != b) {
    unsigned p = atomicAdd(&cursor[a], 1u);
    edgeVal[p] = b;
  }
}

// ---- per-block: 256 buckets sorted in LDS; write back sorted dst + src ids ----
__global__ void __launch_bounds__(256) k_sortlds(unsigned* __restrict__ edgeVal,
                                                 unsigned* __restrict__ edgeSrc,
                                                 const unsigned* __restrict__ bucketStart,
                                                 const unsigned* __restrict__ bucketCnt,
                                                 const unsigned* __restrict__ hdr) {
  __shared__ unsigned dstL[SCAP];
  __shared__ unsigned srcL[SCAP];
  unsigned u0 = blockIdx.x * 256u;
  unsigned u = u0 + threadIdx.x;
  unsigned validE = hdr[4];
  unsigned sBase = bucketStart[u0];
  unsigned sEnd = (u0 + 256u < KSP) ? bucketStart[u0 + 256u] : validE;
  unsigned total = sEnd - sBase;
  unsigned s = bucketStart[u], c = bucketCnt[u];
  if (total <= SCAP) {
    for (unsigned i = threadIdx.x; i < total; i += 256u) dstL[i] = edgeVal[sBase + i];
    __syncthreads();
    unsigned ls = s - sBase;
    for (unsigned i = 1; i < c; ++i) {
      unsigned v = dstL[ls + i];
      int j = (int)i - 1;
      while (j >= 0 && dstL[ls + j] > v) { dstL[ls + j + 1] = dstL[ls + j]; --j; }
      dstL[ls + j + 1] = v;
    }
    for (unsigned i = 0; i < c; ++i) srcL[ls + i] = u;
    __syncthreads();
    for (unsigned i = threadIdx.x; i < total; i += 256u) {
      edgeVal[sBase + i] = dstL[i];
      edgeSrc[sBase + i] = srcL[i];
    }
  } else {  // fallback: sort in global (should never trigger at this distribution)
    for (unsigned i = 1; i < c; ++i) {
      unsigned v = edgeVal[s + i];
      int j = (int)i - 1;
      while (j >= 0 && edgeVal[s + j] > v) { edgeVal[s + j + 1] = edgeVal[s + j]; --j; }
      edgeVal[s + j + 1] = v;
    }
    for (unsigned i = 0; i < c; ++i) edgeSrc[s + i] = u;
  }
}

// ---- per-entry dedup write using scanned ranks ----
__global__ void k_ewrite(const unsigned* __restrict__ edgeSrc, const unsigned* __restrict__ edgeVal,
                         const unsigned* __restrict__ eRank, const unsigned* __restrict__ hdr,
                         float* __restrict__ out) {
  int e = blockIdx.x * blockDim.x + threadIdx.x;
  unsigned n = hdr[4];
  if ((unsigned)e >= n) return;
  unsigned r = eRank[e];
  unsigned nxt = ((unsigned)(e + 1) < n) ? eRank[e + 1] : hdr[5];
  if (nxt > r) {
    unsigned M = hdr[3];
    unsigned long long O2 = 67ull * M;
    out[O2 + 2ull * r + 0] = (float)edgeSrc[e];
    out[O2 + 2ull * r + 1] = (float)edgeVal[e];
  }
}

// ---- self loops + new_batch ----
__global__ void k_final(const unsigned* __restrict__ ukeyArr, const unsigned* __restrict__ hdr,
                        float* __restrict__ out) {
  unsigned m = blockIdx.x * blockDim.x + threadIdx.x;
  unsigned M = hdr[3];
  if (m >= M) return;
  unsigned Ed = hdr[5];
  unsigned long long O2 = 67ull * M;
  unsigned long long row = (unsigned long long)Ed + m;
  float fm = (float)m;
  out[O2 + 2 * row + 0] = fm;
  out[O2 + 2 * row + 1] = fm;
  unsigned s0 = hdr[0] + 1, s1 = hdr[1] + 1, s2 = hdr[2] + 1;
  unsigned vol = s0 * s1 * s2;
  unsigned long long O3 = O2 + 2ull * (Ed + M);
  out[O3 + m] = (float)(ukeyArr[m] / vol);
}

extern "C" void kernel_launch(void* const* d_in, const int* in_sizes, int n_in,
                              void* d_out, int out_size, void* d_ws, size_t ws_size,
                              hipStream_t stream) {
  const float* x = (const float*)d_in[0];
  const float* pos = (const float*)d_in[1];
  const int* ei = (const int*)d_in[2];
  const int* batch = (const int*)d_in[3];
  float* out = (float*)d_out;
  int N = in_sizes[3];
  int E = in_sizes[2] / 2;

  unsigned* ws = (unsigned*)d_ws;
  // ws layout (u32 units)
  unsigned* hdr        = ws;                    // 64
  unsigned* cnt        = ws + 64;               // KSP
  unsigned* bucketCnt  = cnt + KSP;             // KSP
  unsigned* rank       = bucketCnt + KSP;       // KSP
  unsigned* ukeyArr    = rank + KSP;            // KSP
  unsigned* bucketStart= ukeyArr + KSP;         // KSP
  unsigned* cursor     = bucketStart + KSP;     // KSP
  unsigned* chunkSums  = cursor + KSP;          // 1024
  unsigned* key        = chunkSums + 1024;      // N
  unsigned* inv        = key + N;               // N
  unsigned* edgeVal    = inv + N;               // E
  unsigned* edgeSrc    = edgeVal + E;           // E
  unsigned* eStage     = edgeSrc + E;           // E (doubles as eRank)

  // zero: hdr + cnt + bucketCnt (contiguous); all of d_out
  hipMemsetAsync(ws, 0, (size_t)(64 + 2 * KSP) * 4, stream);
  hipMemsetAsync(d_out, 0, (size_t)out_size * 4, stream);

  const int B = 256;
  int gN = (N + B - 1) / B;
  int gE = (E + B - 1) / B;
  int gK = (KSP + B - 1) / B;
  long long totalX = (long long)N * 64;
  int gX = (int)((totalX + B - 1) / B);
  int gD = (int)(((long long)KSP * 64 + B - 1) / B);
  int EC = (E + SCAN_CHUNK - 1) / SCAN_CHUNK;  // edge scan chunks (<=1024)

  k_qmax<<<gN, B, 0, stream>>>(pos, hdr, N);
  k_keys<<<gN, B, 0, stream>>>(pos, batch, hdr, key, cnt, N);

  // rank = exclusive scan of presence(cnt); total -> hdr[3] = M
  scanA<<<NCHUNK, SCAN_BLOCK, 0, stream>>>(cnt, rank, chunkSums, KSP, 1);
  scanB<<<1, 1024, 0, stream>>>(chunkSums, &hdr[3], NCHUNK);
  scanC<<<gK, B, 0, stream>>>(rank, nullptr, chunkSums, KSP);

  k_ukey<<<gK, B, 0, stream>>>(cnt, rank, ukeyArr);
  k_inv_pos<<<gN, B, 0, stream>>>(key, rank, inv, pos, out, hdr, N);
  k_xmax<<<gX, B, 0, stream>>>(x, inv, out, totalX);
  k_decode<<<gD, B, 0, stream>>>(out, hdr);
  k_posdiv<<<gK, B, 0, stream>>>(out, hdr, ukeyArr, cnt);

  // edges
  k_emap<<<gE, B, 0, stream>>>(ei, inv, edgeSrc, eStage, bucketCnt, E);
  scanA<<<NCHUNK, SCAN_BLOCK, 0, stream>>>(bucketCnt, bucketStart, chunkSums, KSP, 0);
  scanB<<<1, 1024, 0, stream>>>(chunkSums, &hdr[4], NCHUNK);
  scanC<<<gK, B, 0, stream>>>(bucketStart, cursor, chunkSums, KSP);
  k_escatter<<<gE, B, 0, stream>>>(edgeSrc, eStage, cursor, edgeVal, E);
  k_sortlds<<<KSP / 256, 256, 0, stream>>>(edgeVal, edgeSrc, bucketStart, bucketCnt, hdr);
  scanAE<<<EC, SCAN_BLOCK, 0, stream>>>(edgeSrc, edgeVal, eStage, chunkSums, hdr);
  scanB<<<1, 1024, 0, stream>>>(chunkSums, &hdr[5], EC);
  scanCE<<<gE, B, 0, stream>>>(eStage, chunkSums, hdr);
  k_ewrite<<<gE, B, 0, stream>>>(edgeSrc, edgeVal, eStage, hdr, out);
  k_final<<<gK, B, 0, stream>>>(ukeyArr, hdr, out);

  (void)n_in; (void)ws_size;
}

// Round 3
// 733.909 us; speedup vs baseline: 1.3719x; 1.3719x over previous
//
#include <hip/hip_runtime.h>

// GraphPooling: voxel-grid pooling.
//  inputs: x[N,64] f32, pos[N,3] f32, edge_index[E,2] i32, batch[N] i32
//  outputs (concat, f32): pooled_x[M,64], pos_mean[M,3], ei_out[Ed+M,2], new_batch[M]
// Keyspace: key = ((b*s0+qx)*s1+qy)*s2+qz < 16*32*32*32 = 524288.
// Edge pipeline: partition by src>>9 (1024 partitions, ~5.8k edges each),
// per-partition LDS counting-sort + dedup. Codes packed as (src<<19)|dst (38 bits).

#define KSP 524288
#define SCAN_BLOCK 256
#define SCAN_ITEMS 16
#define SCAN_CHUNK 4096            // SCAN_BLOCK * SCAN_ITEMS
#define NCHUNK (KSP / SCAN_CHUNK)  // 128
#define NPART 1024
#define PB 512                     // voxel ranks per partition (KSP/NPART)
#define SCAP2 8192                 // LDS cap: edges per partition (mean ~5.8k, sigma ~150)

// ws header slots (u32): [0..2]=max qpos, [3]=M, [4]=validE, [5]=Ed

__device__ __forceinline__ unsigned encF(float f) {
  unsigned u = __float_as_uint(f);
  return (u & 0x80000000u) ? ~u : (u | 0x80000000u);
}
__device__ __forceinline__ float decF(unsigned u) {
  return (u & 0x80000000u) ? __uint_as_float(u & 0x7FFFFFFFu)
                           : __uint_as_float(~u);
}

// ---- per-point: max of quantized coords ----
__global__ void k_qmax(const float* __restrict__ pos, unsigned* hdr, int N) {
  __shared__ unsigned sm[3];
  if (threadIdx.x < 3) sm[threadIdx.x] = 0;
  __syncthreads();
  int i = blockIdx.x * blockDim.x + threadIdx.x;
  if (i < N) {
    int q0 = (int)floorf(pos[3 * i + 0] * 0.25f);
    int q1 = (int)floorf(pos[3 * i + 1] * 0.25f);
    int q2 = (int)floorf(pos[3 * i + 2] * 0.25f);
    atomicMax(&sm[0], (unsigned)q0);
    atomicMax(&sm[1], (unsigned)q1);
    atomicMax(&sm[2], (unsigned)q2);
  }
  __syncthreads();
  if (threadIdx.x < 3) atomicMax(&hdr[threadIdx.x], sm[threadIdx.x]);
}

// ---- per-point: voxel key + histogram ----
__global__ void k_keys(const float* __restrict__ pos, const int* __restrict__ batch,
                       const unsigned* __restrict__ hdr, unsigned* __restrict__ key,
                       unsigned* __restrict__ cnt, int N) {
  int i = blockIdx.x * blockDim.x + threadIdx.x;
  if (i >= N) return;
  unsigned s0 = hdr[0] + 1, s1 = hdr[1] + 1, s2 = hdr[2] + 1;
  unsigned q0 = (unsigned)(int)floorf(pos[3 * i + 0] * 0.25f);
  unsigned q1 = (unsigned)(int)floorf(pos[3 * i + 1] * 0.25f);
  unsigned q2 = (unsigned)(int)floorf(pos[3 * i + 2] * 0.25f);
  unsigned k = (((unsigned)batch[i] * s0 + q0) * s1 + q1) * s2 + q2;
  key[i] = k;
  atomicAdd(&cnt[k], 1u);
}

// ---- 3-phase exclusive scan over KSP ----
__global__ void scanA(const unsigned* __restrict__ in, unsigned* __restrict__ out,
                      unsigned* __restrict__ chunkSums, int n, int presence) {
  __shared__ unsigned lds[SCAN_BLOCK];
  int tbase = blockIdx.x * SCAN_CHUNK + threadIdx.x * SCAN_ITEMS;
  unsigned vals[SCAN_ITEMS];
  unsigned sum = 0;
  for (int i = 0; i < SCAN_ITEMS; ++i) {
    unsigned v = 0;
    int idx = tbase + i;
    if (idx < n) { v = in[idx]; if (presence) v = v ? 1u : 0u; }
    vals[i] = sum;
    sum += v;
  }
  lds[threadIdx.x] = sum;
  __syncthreads();
  for (int off = 1; off < SCAN_BLOCK; off <<= 1) {
    unsigned t = (threadIdx.x >= (unsigned)off) ? lds[threadIdx.x - off] : 0u;
    __syncthreads();
    lds[threadIdx.x] += t;
    __syncthreads();
  }
  unsigned threadExcl = lds[threadIdx.x] - sum;
  for (int i = 0; i < SCAN_ITEMS; ++i) {
    int idx = tbase + i;
    if (idx < n) out[idx] = threadExcl + vals[i];
  }
  if (threadIdx.x == SCAN_BLOCK - 1) chunkSums[blockIdx.x] = lds[SCAN_BLOCK - 1];
}

__global__ void scanB(unsigned* chunkSums, unsigned* totalDst, int nchunks) {
  __shared__ unsigned lds[1024];
  unsigned v = (threadIdx.x < (unsigned)nchunks) ? chunkSums[threadIdx.x] : 0u;
  lds[threadIdx.x] = v;
  __syncthreads();
  for (int off = 1; off < 1024; off <<= 1) {
    unsigned t = (threadIdx.x >= (unsigned)off) ? lds[threadIdx.x - off] : 0u;
    __syncthreads();
    lds[threadIdx.x] += t;
    __syncthreads();
  }
  if (threadIdx.x < (unsigned)nchunks) chunkSums[threadIdx.x] = lds[threadIdx.x] - v;
  if (threadIdx.x == 0 && totalDst) *totalDst = lds[1023];
}

__global__ void scanC(unsigned* __restrict__ out, unsigned* __restrict__ out2,
                      const unsigned* __restrict__ chunkSums, int n) {
  int idx = blockIdx.x * blockDim.x + threadIdx.x;
  if (idx >= n) return;
  unsigned v = out[idx] + chunkSums[idx / SCAN_CHUNK];
  out[idx] = v;
  if (out2) out2[idx] = v;
}

// ---- single-block exclusive scan of NPART entries ----
__global__ void k_scan1024(const unsigned* __restrict__ in, unsigned* __restrict__ outStart,
                           unsigned* __restrict__ outCursor, unsigned* __restrict__ totalDst) {
  __shared__ unsigned lds[NPART];
  unsigned t = threadIdx.x;
  unsigned v = in[t];
  lds[t] = v;
  __syncthreads();
  for (int off = 1; off < NPART; off <<= 1) {
    unsigned x = (t >= (unsigned)off) ? lds[t - off] : 0u;
    __syncthreads();
    lds[t] += x;
    __syncthreads();
  }
  unsigned excl = lds[t] - v;
  outStart[t] = excl;
  if (outCursor) outCursor[t] = excl;
  if (t == NPART - 1) {
    outStart[NPART] = lds[t];
    if (totalDst) *totalDst = lds[t];
  }
}

// ---- build rank -> key map ----
__global__ void k_ukey(const unsigned* __restrict__ cnt, const unsigned* __restrict__ rank,
                       unsigned* __restrict__ ukeyArr) {
  int k = blockIdx.x * blockDim.x + threadIdx.x;
  if (k >= KSP) return;
  if (cnt[k]) ukeyArr[rank[k]] = (unsigned)k;
}

// ---- per-point: inv index + pos accumulation ----
__global__ void k_inv_pos(const unsigned* __restrict__ key, const unsigned* __restrict__ rank,
                          unsigned* __restrict__ inv, const float* __restrict__ pos,
                          float* __restrict__ out, const unsigned* __restrict__ hdr, int N) {
  int i = blockIdx.x * blockDim.x + threadIdx.x;
  if (i >= N) return;
  unsigned m = rank[key[i]];
  inv[i] = m;
  unsigned M = hdr[3];
  unsigned long long O1 = 64ull * M;
  atomicAdd(&out[O1 + 3ull * m + 0], pos[3 * i + 0]);
  atomicAdd(&out[O1 + 3ull * m + 1], pos[3 * i + 1]);
  atomicAdd(&out[O1 + 3ull * m + 2], pos[3 * i + 2]);
}

// ---- per-(point,feature): encoded atomic max ----
__global__ void k_xmax(const float* __restrict__ x, const unsigned* __restrict__ inv,
                       float* __restrict__ out, long long total) {
  long long t = (long long)blockIdx.x * blockDim.x + threadIdx.x;
  if (t >= total) return;
  int i = (int)(t >> 6);
  int d = (int)(t & 63);
  unsigned m = inv[i];
  unsigned e = encF(x[t]);
  atomicMax((unsigned*)&out[(unsigned long long)m * 64u + d], e);
}

__global__ void k_decode(float* __restrict__ out, const unsigned* __restrict__ hdr) {
  long long idx = (long long)blockIdx.x * blockDim.x + threadIdx.x;
  unsigned M = hdr[3];
  if (idx >= (long long)M * 64) return;
  unsigned u = __float_as_uint(out[idx]);
  out[idx] = decF(u);
}

__global__ void k_posdiv(float* __restrict__ out, const unsigned* __restrict__ hdr,
                         const unsigned* __restrict__ ukeyArr, const unsigned* __restrict__ cnt) {
  int m = blockIdx.x * blockDim.x + threadIdx.x;
  unsigned M = hdr[3];
  if ((unsigned)m >= M) return;
  float c = (float)cnt[ukeyArr[m]];
  unsigned long long O1 = 64ull * M;
  out[O1 + 3ull * m + 0] /= c;
  out[O1 + 3ull * m + 1] /= c;
  out[O1 + 3ull * m + 2] /= c;
}

// ---- edges: partition histogram (LDS-aggregated) ----
__global__ void __launch_bounds__(256) k_ehist2(const int2* __restrict__ ei,
                                                const unsigned* __restrict__ inv,
                                                unsigned* __restrict__ partCnt, int E, int span) {
  __shared__ unsigned h[NPART];
  for (int i = threadIdx.x; i < NPART; i += 256) h[i] = 0;
  __syncthreads();
  int lo = blockIdx.x * span;
  int hi = min(E, lo + span);
  for (int e = lo + threadIdx.x; e < hi; e += 256) {
    int2 pr = ei[e];
    unsigned a = inv[pr.x], b = inv[pr.y];
    if (a != b) atomicAdd(&h[a >> 9], 1u);
  }
  __syncthreads();
  for (int i = threadIdx.x; i < NPART; i += 256) {
    unsigned v = h[i];
    if (v) atomicAdd(&partCnt[i], v);
  }
}

// ---- edges: partition scatter (block-reserved contiguous runs) ----
__global__ void __launch_bounds__(256) k_pscatter(const int2* __restrict__ ei,
                                                  const unsigned* __restrict__ inv,
                                                  unsigned* __restrict__ partCursor,
                                                  unsigned long long* __restrict__ pStage,
                                                  int E, int span) {
  __shared__ unsigned h[NPART];
  for (int i = threadIdx.x; i < NPART; i += 256) h[i] = 0;
  __syncthreads();
  int lo = blockIdx.x * span;
  int hi = min(E, lo + span);
  for (int e = lo + threadIdx.x; e < hi; e += 256) {
    int2 pr = ei[e];
    unsigned a = inv[pr.x], b = inv[pr.y];
    if (a != b) atomicAdd(&h[a >> 9], 1u);
  }
  __syncthreads();
  for (int i = threadIdx.x; i < NPART; i += 256) {
    unsigned v = h[i];
    h[i] = v ? atomicAdd(&partCursor[i], v) : 0u;
  }
  __syncthreads();
  for (int e = lo + threadIdx.x; e < hi; e += 256) {
    int2 pr = ei[e];
    unsigned a = inv[pr.x], b = inv[pr.y];
    if (a != b) {
      unsigned off = atomicAdd(&h[a >> 9], 1u);
      pStage[off] = ((unsigned long long)a << 19) | b;
    }
  }
}

// ---- per-partition: LDS counting-sort by src, insertion by dst, dedup+compact ----
__global__ void __launch_bounds__(256) k_bucket(unsigned long long* __restrict__ pStage,
                                                const unsigned* __restrict__ partStart,
                                                unsigned* __restrict__ partDistinct) {
  __shared__ unsigned dstL[SCAP2];
  __shared__ unsigned h[PB];
  __shared__ unsigned bbase[PB + 1];
  __shared__ unsigned dcnt[PB];
  __shared__ unsigned doff[PB + 1];
  __shared__ unsigned stmp[256];
  unsigned p = blockIdx.x;
  unsigned s = partStart[p];
  unsigned c = partStart[p + 1] - s;
  unsigned t = threadIdx.x;
  unsigned srcBase = p << 9;
  for (int i = t; i < PB; i += 256) h[i] = 0;
  __syncthreads();
  if (c <= SCAP2) {
    for (unsigned i = t; i < c; i += 256) {
      unsigned long long code = pStage[s + i];
      atomicAdd(&h[(unsigned)(code >> 19) - srcBase], 1u);
    }
    __syncthreads();
    {  // scan h -> bbase (exclusive)
      unsigned a = h[2 * t], b = h[2 * t + 1], sum = a + b;
      stmp[t] = sum;
      __syncthreads();
      for (int off = 1; off < 256; off <<= 1) {
        unsigned x = (t >= (unsigned)off) ? stmp[t - off] : 0u;
        __syncthreads(); stmp[t] += x; __syncthreads();
      }
      unsigned excl = stmp[t] - sum;
      bbase[2 * t] = excl; bbase[2 * t + 1] = excl + a;
      if (t == 255) bbase[PB] = stmp[255];
    }
    __syncthreads();
    for (int i = t; i < PB; i += 256) h[i] = bbase[i];  // h becomes cursor
    __syncthreads();
    for (unsigned i = t; i < c; i += 256) {
      unsigned long long code = pStage[s + i];
      unsigned b = (unsigned)(code >> 19) - srcBase;
      unsigned off = atomicAdd(&h[b], 1u);
      dstL[off] = (unsigned)(code & 0x7FFFFu);
    }
    __syncthreads();
    for (int b = t; b < PB; b += 256) {  // per-bucket sort + distinct count
      unsigned lo = bbase[b], n = bbase[b + 1] - lo;
      for (unsigned i = 1; i < n; ++i) {
        unsigned v = dstL[lo + i];
        int j = (int)i - 1;
        while (j >= 0 && dstL[lo + j] > v) { dstL[lo + j + 1] = dstL[lo + j]; --j; }
        dstL[lo + j + 1] = v;
      }
      unsigned d = 0, prev = 0;
      for (unsigned i = 0; i < n; ++i) {
        unsigned v = dstL[lo + i];
        if (i == 0 || v != prev) ++d;
        prev = v;
      }
      dcnt[b] = d;
    }
    __syncthreads();
    {  // scan dcnt -> doff (exclusive)
      unsigned a = dcnt[2 * t], b = dcnt[2 * t + 1], sum = a + b;
      stmp[t] = sum;
      __syncthreads();
      for (int off = 1; off < 256; off <<= 1) {
        unsigned x = (t >= (unsigned)off) ? stmp[t - off] : 0u;
        __syncthreads(); stmp[t] += x; __syncthreads();
      }
      unsigned excl = stmp[t] - sum;
      doff[2 * t] = excl; doff[2 * t + 1] = excl + a;
      if (t == 255) doff[PB] = stmp[255];
    }
    __syncthreads();
    for (int b = t; b < PB; b += 256) {  // compact distinct codes back to pStage
      unsigned lo = bbase[b], n = bbase[b + 1] - lo;
      unsigned long long w = (unsigned long long)s + doff[b];
      unsigned long long sb = (unsigned long long)(srcBase + (unsigned)b) << 19;
      unsigned j = 0, prev = 0;
      for (unsigned i = 0; i < n; ++i) {
        unsigned v = dstL[lo + i];
        if (i == 0 || v != prev) { pStage[w + j] = sb | v; ++j; }
        prev = v;
      }
    }
    if (t == 0) partDistinct[p] = doff[PB];
  } else if (t == 0) {  // fallback, statistically unreachable (mean+24sigma)
    for (unsigned i = 1; i < c; ++i) {
      unsigned long long v = pStage[s + i];
      long long j = (long long)i - 1;
      while (j >= 0 && pStage[s + j] > v) { pStage[s + j + 1] = pStage[s + j]; --j; }
      pStage[s + j + 1] = v;
    }
    unsigned d = 0;
    unsigned long long prev = ~0ull;
    for (unsigned i = 0; i < c; ++i) {
      unsigned long long v = pStage[s + i];
      if (i == 0 || v != prev) { pStage[s + d] = v; ++d; }
      prev = v;
    }
    partDistinct[p] = d;
  }
}

// ---- write deduped edges ----
__global__ void __launch_bounds__(256) k_ewriteP(const unsigned long long* __restrict__ pStage,
                                                 const unsigned* __restrict__ partStart,
                                                 const unsigned* __restrict__ partOut,
                                                 const unsigned* __restrict__ hdr,
                                                 float* __restrict__ out) {
  unsigned p = blockIdx.x;
  unsigned s = partStart[p];
  unsigned rbase = partOut[p];
  unsigned d = partOut[p + 1] - rbase;
  unsigned M = hdr[3];
  unsigned long long O2 = 67ull * M;
  for (unsigned j = threadIdx.x; j < d; j += 256) {
    unsigned long long code = pStage[s + j];
    unsigned long long row = (unsigned long long)rbase + j;
    out[O2 + 2 * row + 0] = (float)(unsigned)(code >> 19);
    out[O2 + 2 * row + 1] = (float)(unsigned)(code & 0x7FFFFu);
  }
}

// ---- self loops + new_batch ----
__global__ void k_final(const unsigned* __restrict__ ukeyArr, const unsigned* __restrict__ hdr,
                        float* __restrict__ out) {
  unsigned m = blockIdx.x * blockDim.x + threadIdx.x;
  unsigned M = hdr[3];
  if (m >= M) return;
  unsigned Ed = hdr[5];
  unsigned long long O2 = 67ull * M;
  unsigned long long row = (unsigned long long)Ed + m;
  float fm = (float)m;
  out[O2 + 2 * row + 0] = fm;
  out[O2 + 2 * row + 1] = fm;
  unsigned s0 = hdr[0] + 1, s1 = hdr[1] + 1, s2 = hdr[2] + 1;
  unsigned vol = s0 * s1 * s2;
  unsigned long long O3 = O2 + 2ull * (Ed + M);
  out[O3 + m] = (float)(ukeyArr[m] / vol);
}

extern "C" void kernel_launch(void* const* d_in, const int* in_sizes, int n_in,
                              void* d_out, int out_size, void* d_ws, size_t ws_size,
                              hipStream_t stream) {
  const float* x = (const float*)d_in[0];
  const float* pos = (const float*)d_in[1];
  const int* ei = (const int*)d_in[2];
  const int* batch = (const int*)d_in[3];
  float* out = (float*)d_out;
  int N = in_sizes[3];
  int E = in_sizes[2] / 2;

  unsigned* ws = (unsigned*)d_ws;
  // ws layout (u32 units)
  unsigned* hdr          = ws;                        // 64
  unsigned* cnt          = ws + 64;                   // KSP
  unsigned* partCnt      = cnt + KSP;                 // NPART
  unsigned* partDistinct = partCnt + NPART;           // NPART
  unsigned* rank         = partDistinct + NPART;      // KSP
  unsigned* ukeyArr      = rank + KSP;                // KSP
  unsigned* partStart    = ukeyArr + KSP;             // NPART+2
  unsigned* partCursor   = partStart + NPART + 2;     // NPART
  unsigned* partOut      = partCursor + NPART;        // NPART+2
  unsigned* chunkSums    = partOut + NPART + 2;       // 1024
  unsigned* key          = chunkSums + 1024;          // N
  unsigned* inv          = key + N;                   // N
  unsigned* pS32         = inv + ((N + 1) & ~1);      // 8B-aligned
  unsigned long long* pStage = (unsigned long long*)pS32;  // E u64

  // zero: hdr + cnt + partCnt + partDistinct (contiguous); all of d_out
  hipMemsetAsync(ws, 0, (size_t)(64 + KSP + 2 * NPART) * 4, stream);
  hipMemsetAsync(d_out, 0, (size_t)out_size * 4, stream);

  const int B = 256;
  int gN = (N + B - 1) / B;
  int gK = (KSP + B - 1) / B;
  long long totalX = (long long)N * 64;
  int gX = (int)((totalX + B - 1) / B);
  int gD = (int)(((long long)KSP * 64 + B - 1) / B);
  int span = (E + 255) / 256;  // edges per block for the 256-block edge passes

  k_qmax<<<gN, B, 0, stream>>>(pos, hdr, N);
  k_keys<<<gN, B, 0, stream>>>(pos, batch, hdr, key, cnt, N);

  // rank = exclusive scan of presence(cnt); total -> hdr[3] = M
  scanA<<<NCHUNK, SCAN_BLOCK, 0, stream>>>(cnt, rank, chunkSums, KSP, 1);
  scanB<<<1, 1024, 0, stream>>>(chunkSums, &hdr[3], NCHUNK);
  scanC<<<gK, B, 0, stream>>>(rank, nullptr, chunkSums, KSP);

  k_ukey<<<gK, B, 0, stream>>>(cnt, rank, ukeyArr);
  k_inv_pos<<<gN, B, 0, stream>>>(key, rank, inv, pos, out, hdr, N);
  k_xmax<<<gX, B, 0, stream>>>(x, inv, out, totalX);
  k_decode<<<gD, B, 0, stream>>>(out, hdr);
  k_posdiv<<<gK, B, 0, stream>>>(out, hdr, ukeyArr, cnt);

  // edges: partition -> LDS sort/dedup -> write
  const int2* ei2 = (const int2*)ei;
  k_ehist2<<<256, 256, 0, stream>>>(ei2, inv, partCnt, E, span);
  k_scan1024<<<1, NPART, 0, stream>>>(partCnt, partStart, partCursor, &hdr[4]);
  k_pscatter<<<256, 256, 0, stream>>>(ei2, inv, partCursor, pStage, E, span);
  k_bucket<<<NPART, 256, 0, stream>>>(pStage, partStart, partDistinct);
  k_scan1024<<<1, NPART, 0, stream>>>(partDistinct, partOut, nullptr, &hdr[5]);
  k_ewriteP<<<NPART, 256, 0, stream>>>(pStage, partStart, partOut, hdr, out);
  k_final<<<gK, B, 0, stream>>>(ukeyArr, hdr, out);

  (void)n_in; (void)ws_size;
}